// Round 12
// baseline (273.277 us; speedup 1.0000x reference)
//
#include <hip/hip_runtime.h>

#define TQ_D   1024
#define TQ_KC  16
#define BM     128
#define BN     64
#define BK     16
#define NTILES (TQ_D / BK)   // 64
#define MERGE_TILE 32        // k=512: OpenBLAS KC-panel boundary (proven R9)
#define LDA    (BM + 4)      // 132
#define LDB    (BN + 4)      // 68

// ---------------------------------------------------------------------------
// Kernel 1: y = x @ Pi^T (NT GEMM), f32, EXACT reference realization (R9):
// serial ascending-k FMA chain per element within KC=512 panels, one f32
// panel-merge add, literal f32 argmin (first strict min).
// Panel-1 subtotal parked in GLOBAL scratch (the x_hat region, overwritten
// by K2 later): avoids both the R10 VGPR spill and the R11 32KB-LDS
// occupancy squeeze. f32 store/load round-trip is bit-exact.
// ---------------------------------------------------------------------------
__global__ __launch_bounds__(256, 2)
void tq_rotate_quant(const float* __restrict__ X,
                     const float* __restrict__ Pi,
                     const float* __restrict__ Cent,
                     float* __restrict__ OutIdx,
                     float* __restrict__ Ypart)
{
    __shared__ float As[BK][LDA];
    __shared__ float Bs[BK][LDB];

    const int tid = threadIdx.x;
    const int bid = blockIdx.y * gridDim.x + blockIdx.x;
    const int m0 = blockIdx.y * BM;
    const int n0 = blockIdx.x * BN;
    const int tx = tid & 15;   // cols tx*4 .. tx*4+3
    const int ty = tid >> 4;   // rows ty*4 (+64 for frag 1)

    const int rr = tid >> 2;   // 0..63
    const int cc = tid & 3;    // k-quad

    const float* aPtr = X  + (size_t)(m0 + rr) * TQ_D + (cc << 2);
    const float* bPtr = Pi + (size_t)(n0 + rr) * TQ_D + (cc << 2);

    // per-block frag-major scratch slab: [32 frags][256 tids]
    float* yp = Ypart + (size_t)bid * 32 * 256;

    float acc[2][4][4];
#pragma unroll
    for (int r = 0; r < 2; ++r)
#pragma unroll
        for (int i = 0; i < 4; ++i)
#pragma unroll
            for (int j = 0; j < 4; ++j) acc[r][i][j] = 0.0f;

    // stage tile 0
    float4 va0 = *(const float4*)(aPtr);
    float4 va1 = *(const float4*)(aPtr + (size_t)64 * TQ_D);
    float4 vb0 = *(const float4*)(bPtr);
#pragma unroll
    for (int q = 0; q < 4; ++q) {
        As[(cc << 2) + q][rr]      = ((const float*)&va0)[q];
        As[(cc << 2) + q][rr + 64] = ((const float*)&va1)[q];
        Bs[(cc << 2) + q][rr]      = ((const float*)&vb0)[q];
    }
    __syncthreads();

    for (int kt = 0; kt < NTILES; ++kt) {
        if (kt == MERGE_TILE) {   // KC=512 boundary: park S1 in global, restart
#pragma unroll
            for (int r = 0; r < 2; ++r)
#pragma unroll
                for (int i = 0; i < 4; ++i)
#pragma unroll
                    for (int j = 0; j < 4; ++j) {
                        const int f = (r << 4) + (i << 2) + j;
                        yp[(size_t)f * 256 + tid] = acc[r][i][j];
                        acc[r][i][j] = 0.0f;
                    }
        }

        const bool more = (kt + 1) < NTILES;
        if (more) {
            const float* ap = aPtr + (kt + 1) * BK;
            const float* bp = bPtr + (kt + 1) * BK;
            va0 = *(const float4*)(ap);
            va1 = *(const float4*)(ap + (size_t)64 * TQ_D);
            vb0 = *(const float4*)(bp);
        }
#pragma unroll
        for (int k = 0; k < BK; ++k) {
            const float4 a0 = *(const float4*)&As[k][ty << 2];
            const float4 a1 = *(const float4*)&As[k][64 + (ty << 2)];
            const float4 b0 = *(const float4*)&Bs[k][tx << 2];
            const float a0v[4] = {a0.x, a0.y, a0.z, a0.w};
            const float a1v[4] = {a1.x, a1.y, a1.z, a1.w};
            const float bv[4]  = {b0.x, b0.y, b0.z, b0.w};
#pragma unroll
            for (int i = 0; i < 4; ++i)
#pragma unroll
                for (int j = 0; j < 4; ++j) {
                    acc[0][i][j] = fmaf(a0v[i], bv[j], acc[0][i][j]);
                    acc[1][i][j] = fmaf(a1v[i], bv[j], acc[1][i][j]);
                }
        }
        if (more) {
            __syncthreads();
#pragma unroll
            for (int q = 0; q < 4; ++q) {
                As[(cc << 2) + q][rr]      = ((const float*)&va0)[q];
                As[(cc << 2) + q][rr + 64] = ((const float*)&va1)[q];
                Bs[(cc << 2) + q][rr]      = ((const float*)&vb0)[q];
            }
            __syncthreads();
        }
    }

    float c[TQ_KC];
#pragma unroll
    for (int q = 0; q < TQ_KC; ++q) c[q] = Cent[q];

#pragma unroll
    for (int r = 0; r < 2; ++r)
#pragma unroll
        for (int i = 0; i < 4; ++i) {
            const int m = m0 + (r << 6) + (ty << 2) + i;
            float o[4];
#pragma unroll
            for (int j = 0; j < 4; ++j) {
                const int f = (r << 4) + (i << 2) + j;
                // y = S1 (global park, same-block L2 hit) + S2 — exact R9 merge
                const float y = yp[(size_t)f * 256 + tid] + acc[r][i][j];
                int best = 0;
                float bd = fabsf(y - c[0]);
#pragma unroll
                for (int q = 1; q < TQ_KC; ++q) {
                    const float d = fabsf(y - c[q]);
                    if (d < bd) { bd = d; best = q; }
                }
                o[j] = (float)best;
            }
            *(float4*)(OutIdx + (size_t)m * TQ_D + n0 + (tx << 2)) =
                make_float4(o[0], o[1], o[2], o[3]);
        }
}

// ---------------------------------------------------------------------------
// Kernel 2: x_hat = dequant(idx) @ Pi (NN GEMM, f32) — UNCHANGED (measured
// ~53us, at the f32 vector-FMA roofline). Overwrites the Ypart scratch.
// ---------------------------------------------------------------------------
__global__ __launch_bounds__(256, 2)
void tq_dequant_unrotate(const float* __restrict__ IdxF,
                         const float* __restrict__ Pi,
                         const float* __restrict__ Cent,
                         float* __restrict__ Xhat)
{
    __shared__ float As[BK][LDA];
    __shared__ float Bs[BK][LDB];
    __shared__ float cs[TQ_KC];

    const int tid = threadIdx.x;
    const int m0 = blockIdx.y * BM;
    const int n0 = blockIdx.x * BN;
    const int tx = tid & 15;
    const int ty = tid >> 4;

    const int rr = tid >> 2;
    const int cc = tid & 3;
    const int kr = tid >> 4;
    const int cq = tid & 15;

    const float* aPtr = IdxF + (size_t)(m0 + rr) * TQ_D + (cc << 2);
    const float* pPtr = Pi + (size_t)kr * TQ_D + n0 + (cq << 2);

    if (tid < TQ_KC) cs[tid] = Cent[tid];

    float acc[2][4][4];
#pragma unroll
    for (int r = 0; r < 2; ++r)
#pragma unroll
        for (int i = 0; i < 4; ++i)
#pragma unroll
            for (int j = 0; j < 4; ++j) acc[r][i][j] = 0.0f;

    float4 va0 = *(const float4*)(aPtr);
    float4 va1 = *(const float4*)(aPtr + (size_t)64 * TQ_D);
    float4 vb0 = *(const float4*)(pPtr);
    __syncthreads();   // cs[] ready
#pragma unroll
    for (int q = 0; q < 4; ++q) {
        As[(cc << 2) + q][rr]      = cs[((int)((const float*)&va0)[q]) & 15];
        As[(cc << 2) + q][rr + 64] = cs[((int)((const float*)&va1)[q]) & 15];
    }
    *(float4*)&Bs[kr][cq << 2] = vb0;
    __syncthreads();

    for (int kt = 0; kt < NTILES; ++kt) {
        const bool more = (kt + 1) < NTILES;
        if (more) {
            const float* ap = aPtr + (kt + 1) * BK;
            const float* bp = pPtr + (size_t)(kt + 1) * BK * TQ_D;
            va0 = *(const float4*)(ap);
            va1 = *(const float4*)(ap + (size_t)64 * TQ_D);
            vb0 = *(const float4*)(bp);
        }
#pragma unroll
        for (int k = 0; k < BK; ++k) {
            const float4 a0 = *(const float4*)&As[k][ty << 2];
            const float4 a1 = *(const float4*)&As[k][64 + (ty << 2)];
            const float4 b0 = *(const float4*)&Bs[k][tx << 2];
            const float a0v[4] = {a0.x, a0.y, a0.z, a0.w};
            const float a1v[4] = {a1.x, a1.y, a1.z, a1.w};
            const float bv[4]  = {b0.x, b0.y, b0.z, b0.w};
#pragma unroll
            for (int i = 0; i < 4; ++i)
#pragma unroll
                for (int j = 0; j < 4; ++j) {
                    acc[0][i][j] = fmaf(a0v[i], bv[j], acc[0][i][j]);
                    acc[1][i][j] = fmaf(a1v[i], bv[j], acc[1][i][j]);
                }
        }
        if (more) {
            __syncthreads();
#pragma unroll
            for (int q = 0; q < 4; ++q) {
                As[(cc << 2) + q][rr]      = cs[((int)((const float*)&va0)[q]) & 15];
                As[(cc << 2) + q][rr + 64] = cs[((int)((const float*)&va1)[q]) & 15];
            }
            *(float4*)&Bs[kr][cq << 2] = vb0;
            __syncthreads();
        }
    }

#pragma unroll
    for (int r = 0; r < 2; ++r)
#pragma unroll
        for (int i = 0; i < 4; ++i) {
            const int m = m0 + (r << 6) + (ty << 2) + i;
            *(float4*)(Xhat + (size_t)m * TQ_D + n0 + (tx << 2)) =
                make_float4(acc[r][i][0], acc[r][i][1], acc[r][i][2], acc[r][i][3]);
        }
}

// ---------------------------------------------------------------------------
extern "C" void kernel_launch(void* const* d_in, const int* in_sizes, int n_in,
                              void* d_out, int out_size, void* d_ws, size_t ws_size,
                              hipStream_t stream)
{
    const float* x    = (const float*)d_in[0];   // [N, 1024]
    const float* Pi   = (const float*)d_in[1];   // [1024, 1024]
    const float* cent = (const float*)d_in[2];   // [16]
    float* out = (float*)d_out;

    const int ND = in_sizes[0];      // N * 1024
    const int N  = ND / TQ_D;        // 4096

    float* xhat = out;               // output 0: [N,1024] f32 (+ K1 scratch)
    float* oidx = out + ND;          // output 1: indices as float

    dim3 grid(TQ_D / BN, N / BM);    // (16, 32) = 512 blocks
    // K1 parks its panel-1 subtotal in the xhat region (512 blocks * 32KB
    // = ND floats exactly); K2 then overwrites xhat with the real output.
    tq_rotate_quant<<<grid, 256, 0, stream>>>(x, Pi, cent, oidx, xhat);
    tq_dequant_unrotate<<<grid, 256, 0, stream>>>(oidx, Pi, cent, xhat);
}

// Round 13
// 245.693 us; speedup vs baseline: 1.1123x; 1.1123x over previous
//
#include <hip/hip_runtime.h>

#define TQ_D   1024
#define TQ_KC  16
#define BK     16
#define NTILES (TQ_D / BK)   // 64
#define MERGE_TILE 32        // k=512: OpenBLAS KC-panel boundary (proven R9)

// ---- K1: 64x64 tile, 4x4/thread, dual in-reg panel accumulators ----
#define K1_B   64
#define K1_LD  (K1_B + 4)    // 68

// ---- K2: 128x64 tile (unchanged, at f32 FMA roofline ~53us) ----
#define BM     128
#define BN     64
#define LDA    (BM + 4)      // 132
#define LDB    (BN + 4)      // 68

// ---------------------------------------------------------------------------
// Kernel 1: y = x @ Pi^T (NT GEMM), f32, EXACT reference realization (R9):
// serial ascending-k FMA chain per element within KC=512 panels, one f32
// panel-merge add, literal f32 argmin (first strict min).
// 64x64 tile -> 16 acc + 16 ysum regs (no spill, no park), 1024 blocks
// (4/CU, ~50% occupancy) to hide staging latency.
// ---------------------------------------------------------------------------
__global__ __launch_bounds__(256, 4)
void tq_rotate_quant(const float* __restrict__ X,
                     const float* __restrict__ Pi,
                     const float* __restrict__ Cent,
                     float* __restrict__ OutIdx)
{
    __shared__ float As[BK][K1_LD];
    __shared__ float Bs[BK][K1_LD];

    const int tid = threadIdx.x;
    const int m0 = blockIdx.y * K1_B;
    const int n0 = blockIdx.x * K1_B;
    const int tx = tid & 15;   // col group: cols n0 + tx*4 .. +3
    const int ty = tid >> 4;   // row group: rows m0 + ty*4 .. +3

    const int rr = tid >> 2;   // staging row 0..63
    const int cc = tid & 3;    // staging k-quad

    const float* aPtr = X  + (size_t)(m0 + rr) * TQ_D + (cc << 2);
    const float* bPtr = Pi + (size_t)(n0 + rr) * TQ_D + (cc << 2);

    float acc[4][4];    // current-panel serial FMA accumulator
    float ysum[4][4];   // panel-1 subtotal (registers — fits now)
#pragma unroll
    for (int i = 0; i < 4; ++i)
#pragma unroll
        for (int j = 0; j < 4; ++j) { acc[i][j] = 0.0f; ysum[i][j] = 0.0f; }

    // stage tile 0
    float4 va = *(const float4*)(aPtr);
    float4 vb = *(const float4*)(bPtr);
#pragma unroll
    for (int q = 0; q < 4; ++q) {
        As[(cc << 2) + q][rr] = ((const float*)&va)[q];
        Bs[(cc << 2) + q][rr] = ((const float*)&vb)[q];
    }
    __syncthreads();

    for (int kt = 0; kt < NTILES; ++kt) {
        if (kt == MERGE_TILE) {   // KC=512 boundary: swap to panel-2 accumulator
#pragma unroll
            for (int i = 0; i < 4; ++i)
#pragma unroll
                for (int j = 0; j < 4; ++j) { ysum[i][j] = acc[i][j]; acc[i][j] = 0.0f; }
        }

        const bool more = (kt + 1) < NTILES;
        if (more) {
            va = *(const float4*)(aPtr + (kt + 1) * BK);
            vb = *(const float4*)(bPtr + (kt + 1) * BK);
        }
#pragma unroll
        for (int k = 0; k < BK; ++k) {
            const float4 a0 = *(const float4*)&As[k][ty << 2];
            const float4 b0 = *(const float4*)&Bs[k][tx << 2];
            const float av[4] = {a0.x, a0.y, a0.z, a0.w};
            const float bv[4] = {b0.x, b0.y, b0.z, b0.w};
#pragma unroll
            for (int i = 0; i < 4; ++i)
#pragma unroll
                for (int j = 0; j < 4; ++j)
                    acc[i][j] = fmaf(av[i], bv[j], acc[i][j]);
        }
        if (more) {
            __syncthreads();
#pragma unroll
            for (int q = 0; q < 4; ++q) {
                As[(cc << 2) + q][rr] = ((const float*)&va)[q];
                Bs[(cc << 2) + q][rr] = ((const float*)&vb)[q];
            }
            __syncthreads();
        }
    }

    float c[TQ_KC];
#pragma unroll
    for (int q = 0; q < TQ_KC; ++q) c[q] = Cent[q];

#pragma unroll
    for (int i = 0; i < 4; ++i) {
        const int m = m0 + (ty << 2) + i;
        float o[4];
#pragma unroll
        for (int j = 0; j < 4; ++j) {
            const float y = ysum[i][j] + acc[i][j];   // exact R9 panel merge
            int best = 0;
            float bd = fabsf(y - c[0]);
#pragma unroll
            for (int q = 1; q < TQ_KC; ++q) {
                const float d = fabsf(y - c[q]);
                if (d < bd) { bd = d; best = q; }
            }
            o[j] = (float)best;
        }
        *(float4*)(OutIdx + (size_t)m * TQ_D + n0 + (tx << 2)) =
            make_float4(o[0], o[1], o[2], o[3]);
    }
}

// ---------------------------------------------------------------------------
// Kernel 2: x_hat = dequant(idx) @ Pi (NN GEMM, f32) — UNCHANGED (measured
// ~53us, at the f32 vector-FMA roofline).
// ---------------------------------------------------------------------------
__global__ __launch_bounds__(256, 2)
void tq_dequant_unrotate(const float* __restrict__ IdxF,
                         const float* __restrict__ Pi,
                         const float* __restrict__ Cent,
                         float* __restrict__ Xhat)
{
    __shared__ float As[BK][LDA];
    __shared__ float Bs[BK][LDB];
    __shared__ float cs[TQ_KC];

    const int tid = threadIdx.x;
    const int m0 = blockIdx.y * BM;
    const int n0 = blockIdx.x * BN;
    const int tx = tid & 15;
    const int ty = tid >> 4;

    const int rr = tid >> 2;
    const int cc = tid & 3;
    const int kr = tid >> 4;
    const int cq = tid & 15;

    const float* aPtr = IdxF + (size_t)(m0 + rr) * TQ_D + (cc << 2);
    const float* pPtr = Pi + (size_t)kr * TQ_D + n0 + (cq << 2);

    if (tid < TQ_KC) cs[tid] = Cent[tid];

    float acc[2][4][4];
#pragma unroll
    for (int r = 0; r < 2; ++r)
#pragma unroll
        for (int i = 0; i < 4; ++i)
#pragma unroll
            for (int j = 0; j < 4; ++j) acc[r][i][j] = 0.0f;

    float4 va0 = *(const float4*)(aPtr);
    float4 va1 = *(const float4*)(aPtr + (size_t)64 * TQ_D);
    float4 vb0 = *(const float4*)(pPtr);
    __syncthreads();   // cs[] ready
#pragma unroll
    for (int q = 0; q < 4; ++q) {
        As[(cc << 2) + q][rr]      = cs[((int)((const float*)&va0)[q]) & 15];
        As[(cc << 2) + q][rr + 64] = cs[((int)((const float*)&va1)[q]) & 15];
    }
    *(float4*)&Bs[kr][cq << 2] = vb0;
    __syncthreads();

    for (int kt = 0; kt < NTILES; ++kt) {
        const bool more = (kt + 1) < NTILES;
        if (more) {
            const float* ap = aPtr + (kt + 1) * BK;
            const float* bp = pPtr + (size_t)(kt + 1) * BK * TQ_D;
            va0 = *(const float4*)(ap);
            va1 = *(const float4*)(ap + (size_t)64 * TQ_D);
            vb0 = *(const float4*)(bp);
        }
#pragma unroll
        for (int k = 0; k < BK; ++k) {
            const float4 a0 = *(const float4*)&As[k][ty << 2];
            const float4 a1 = *(const float4*)&As[k][64 + (ty << 2)];
            const float4 b0 = *(const float4*)&Bs[k][tx << 2];
            const float a0v[4] = {a0.x, a0.y, a0.z, a0.w};
            const float a1v[4] = {a1.x, a1.y, a1.z, a1.w};
            const float bv[4]  = {b0.x, b0.y, b0.z, b0.w};
#pragma unroll
            for (int i = 0; i < 4; ++i)
#pragma unroll
                for (int j = 0; j < 4; ++j) {
                    acc[0][i][j] = fmaf(a0v[i], bv[j], acc[0][i][j]);
                    acc[1][i][j] = fmaf(a1v[i], bv[j], acc[1][i][j]);
                }
        }
        if (more) {
            __syncthreads();
#pragma unroll
            for (int q = 0; q < 4; ++q) {
                As[(cc << 2) + q][rr]      = cs[((int)((const float*)&va0)[q]) & 15];
                As[(cc << 2) + q][rr + 64] = cs[((int)((const float*)&va1)[q]) & 15];
            }
            *(float4*)&Bs[kr][cq << 2] = vb0;
            __syncthreads();
        }
    }

#pragma unroll
    for (int r = 0; r < 2; ++r)
#pragma unroll
        for (int i = 0; i < 4; ++i) {
            const int m = m0 + (r << 6) + (ty << 2) + i;
            *(float4*)(Xhat + (size_t)m * TQ_D + n0 + (tx << 2)) =
                make_float4(acc[r][i][0], acc[r][i][1], acc[r][i][2], acc[r][i][3]);
        }
}

// ---------------------------------------------------------------------------
extern "C" void kernel_launch(void* const* d_in, const int* in_sizes, int n_in,
                              void* d_out, int out_size, void* d_ws, size_t ws_size,
                              hipStream_t stream)
{
    const float* x    = (const float*)d_in[0];   // [N, 1024]
    const float* Pi   = (const float*)d_in[1];   // [1024, 1024]
    const float* cent = (const float*)d_in[2];   // [16]
    float* out = (float*)d_out;

    const int ND = in_sizes[0];      // N * 1024
    const int N  = ND / TQ_D;        // 4096

    float* xhat = out;               // output 0: [N,1024] f32
    float* oidx = out + ND;          // output 1: indices as float

    dim3 grid1(TQ_D / K1_B, N / K1_B);   // (16, 64) = 1024 blocks (4/CU)
    tq_rotate_quant<<<grid1, 256, 0, stream>>>(x, Pi, cent, oidx);

    dim3 grid2(TQ_D / BN, N / BM);       // (16, 32) = 512 blocks
    tq_dequant_unrotate<<<grid2, 256, 0, stream>>>(oidx, Pi, cent, xhat);
}